// Round 1
// baseline (165.594 us; speedup 1.0000x reference)
//
#include <hip/hip_runtime.h>
#include <math.h>

namespace {
constexpr int kB    = 64;
constexpr int kH    = 32;
constexpr int kKVH  = 8;
constexpr int kG    = 4;    // H / KVH
constexpr int kD    = 128;
constexpr int kBS   = 128;
constexpr int kNBPS = 16;
constexpr int kWaves = 8;   // 512 threads
constexpr float kScale = 0.08838834764831845f; // 1/sqrt(128)
}

__global__ __launch_bounds__(512, 4)
void pa_decode_kernel(const float* __restrict__ q,
                      const float* __restrict__ knew,
                      const float* __restrict__ vnew,
                      const float* __restrict__ kcache,
                      const float* __restrict__ vcache,
                      const int* __restrict__ block_tables,
                      const int* __restrict__ ctx_lens,
                      float* __restrict__ out)
{
  const int job  = blockIdx.x;
  const int b    = job >> 3;   // / kKVH
  const int kvh  = job & 7;
  const int tid  = threadIdx.x;
  const int wave = tid >> 6;
  const int lane = tid & 63;
  const int grp  = lane >> 5;  // 0: even position of pair, 1: odd
  const int l32  = lane & 31;

  __shared__ int   bt[kNBPS];
  __shared__ float red_m[kWaves][kG];
  __shared__ float red_l[kWaves][kG];
  __shared__ float red_acc[kWaves][kG][kD];

  if (tid < kNBPS) bt[tid] = block_tables[b * kNBPS + tid];
  const int ctx = ctx_lens[b];
  __syncthreads();

  // q fragment: head g, dims [l32*4, l32*4+4)
  float4 qf[kG];
#pragma unroll
  for (int g = 0; g < kG; ++g)
    qf[g] = *reinterpret_cast<const float4*>(q + (b * kH + kvh * kG + g) * kD + l32 * 4);

  float  m[kG], l[kG];
  float2 acc[kG];   // lane owns d = lane*2, lane*2+1
#pragma unroll
  for (int g = 0; g < kG; ++g) { m[g] = -INFINITY; l[g] = 0.f; acc[g] = make_float2(0.f, 0.f); }

  const float* knew_row = knew + (b * kKVH + kvh) * kD;
  const float* vnew_row = vnew + (b * kKVH + kvh) * kD;
  const int last   = ctx - 1;
  const int npairs = (ctx + 1) >> 1;

  for (int pair = wave; pair < npairs; pair += kWaves) {
    const int  pe      = pair * 2;          // even position, always < ctx
    const bool ovalid  = (pe + 1) < ctx;    // odd position valid?
    const int  myp     = (grp && ovalid) ? (pe + 1) : pe;
    const bool myvalid = (!grp) || ovalid;

    // ---- issue all loads for this pair up front ----
    const float* krow = (myp == last) ? knew_row
        : kcache + ((bt[myp >> 7] * kBS + (myp & 127)) * kKVH + kvh) * kD;
    const float4 kf = *reinterpret_cast<const float4*>(krow + l32 * 4);

    const int poc = ovalid ? (pe + 1) : pe;
    const float* vrow_e = (pe == last) ? vnew_row
        : vcache + ((bt[pe >> 7] * kBS + (pe & 127)) * kKVH + kvh) * kD;
    const float* vrow_o = (poc == last) ? vnew_row
        : vcache + ((bt[poc >> 7] * kBS + (poc & 127)) * kKVH + kvh) * kD;
    const float2 ve = *reinterpret_cast<const float2*>(vrow_e + lane * 2);
    const float2 vo = *reinterpret_cast<const float2*>(vrow_o + lane * 2);

    // ---- 4-head dot products, reduced over the 32-lane group ----
    float s[kG];
#pragma unroll
    for (int g = 0; g < kG; ++g) {
      s[g] = qf[g].x * kf.x;
      s[g] = fmaf(qf[g].y, kf.y, s[g]);
      s[g] = fmaf(qf[g].z, kf.z, s[g]);
      s[g] = fmaf(qf[g].w, kf.w, s[g]);
    }
#pragma unroll
    for (int off = 1; off < 32; off <<= 1) {
#pragma unroll
      for (int g = 0; g < kG; ++g) s[g] += __shfl_xor(s[g], off);
    }
#pragma unroll
    for (int g = 0; g < kG; ++g)
      s[g] = myvalid ? s[g] * kScale : -INFINITY;

    // exchange across the 32-boundary: every lane gets both positions' scores
    float se[kG], so[kG];
#pragma unroll
    for (int g = 0; g < kG; ++g) {
      const float s2 = __shfl_xor(s[g], 32);
      se[g] = grp ? s2   : s[g];
      so[g] = grp ? s[g] : s2;
    }

    // ---- online softmax + V accumulation ----
#pragma unroll
    for (int g = 0; g < kG; ++g) {
      const float pm = fmaxf(se[g], so[g]);   // finite: pe always valid
      if (pm > m[g]) {                        // wave-uniform branch
        const float cf = __expf(m[g] - pm);   // expf(-inf)=0 on first hit
        m[g] = pm;
        l[g] *= cf;
        acc[g].x *= cf;
        acc[g].y *= cf;
      }
      const float ee = __expf(se[g] - m[g]);
      const float eo = __expf(so[g] - m[g]);  // 0 if odd invalid
      l[g] += ee + eo;
      acc[g].x = fmaf(ee, ve.x, fmaf(eo, vo.x, acc[g].x));
      acc[g].y = fmaf(ee, ve.y, fmaf(eo, vo.y, acc[g].y));
    }
  }

  // ---- combine 8 wave-local states (flash-decoding style) ----
  if (lane == 0) {
#pragma unroll
    for (int g = 0; g < kG; ++g) { red_m[wave][g] = m[g]; red_l[wave][g] = l[g]; }
  }
#pragma unroll
  for (int g = 0; g < kG; ++g) {
    red_acc[wave][g][lane * 2]     = acc[g].x;
    red_acc[wave][g][lane * 2 + 1] = acc[g].y;
  }
  __syncthreads();

  const int g = tid >> 7;     // 512 threads -> 4 heads x 128 dims
  const int d = tid & 127;
  float M = -INFINITY;
#pragma unroll
  for (int w = 0; w < kWaves; ++w) M = fmaxf(M, red_m[w][g]);
  float L = 0.f, o = 0.f;
#pragma unroll
  for (int w = 0; w < kWaves; ++w) {
    const float f = __expf(red_m[w][g] - M);  // 0 for empty waves
    L = fmaf(f, red_l[w][g], L);
    o = fmaf(f, red_acc[w][g][d], o);
  }
  out[(b * kH + kvh * kG + g) * kD + d] = o / L;
}

extern "C" void kernel_launch(void* const* d_in, const int* in_sizes, int n_in,
                              void* d_out, int out_size, void* d_ws, size_t ws_size,
                              hipStream_t stream) {
  const float* q  = (const float*)d_in[0];
  const float* k  = (const float*)d_in[1];
  const float* v  = (const float*)d_in[2];
  const float* kc = (const float*)d_in[3];
  const float* vc = (const float*)d_in[4];
  // d_in[5] = slot_mapping (derivable from block_tables/context_lens; unused)
  const int* block_tables = (const int*)d_in[6];
  const int* ctx_lens     = (const int*)d_in[7];
  float* out = (float*)d_out;

  pa_decode_kernel<<<kB * kKVH, 512, 0, stream>>>(q, k, v, kc, vc,
                                                  block_tables, ctx_lens, out);
}